// Round 1
// baseline (71.708 us; speedup 1.0000x reference)
//
#include <hip/hip_runtime.h>

#define BATCH   131072
#define NBLK    512     // BATCH / 256

// ---------------------------------------------------------------------------
// Kernel 1: one thread per sample.
//   pool 24x24 -> 16, encode -> 4 angles, simulate 4-qubit circuit in regs,
//   MLP 4->32->4, write pre-BN output [B,4] to d_out, and write per-block
//   partial sums (sum, sumsq per feature) to d_ws (deterministic, no atomics).
// ---------------------------------------------------------------------------
__global__ __launch_bounds__(256) void qnat_main(
    const float* __restrict__ x,
    const float* __restrict__ Wenc, const float* __restrict__ benc,
    const float* __restrict__ W1,   const float* __restrict__ b1,
    const float* __restrict__ W2,   const float* __restrict__ b2,
    float* __restrict__ out_pre, float* __restrict__ partials)
{
    // Weight staging in LDS: Wenc[64] | benc[4] | W1[128] | b1[32] | W2[128] | b2[4]
    __shared__ float sW[360];
    const int t = threadIdx.x;
    if (t < 64)  sW[t]       = Wenc[t];
    if (t < 4)   sW[64 + t]  = benc[t];
    if (t < 128) sW[68 + t]  = W1[t];
    if (t < 32)  sW[196 + t] = b1[t];
    if (t < 128) sW[228 + t] = W2[t];
    if (t < 4)   sW[356 + t] = b2[t];
    __syncthreads();

    const int s = blockIdx.x * 256 + t;
    const float4* xp = reinterpret_cast<const float4*>(x + (size_t)s * 576);

    // ---- avg_pool2d 6x6: 24x24 -> 4x4 (all indices compile-time static) ----
    float pooled[16];
    #pragma unroll
    for (int pr = 0; pr < 4; ++pr) {
        float a0 = 0.f, a1 = 0.f, a2 = 0.f, a3 = 0.f;
        #pragma unroll
        for (int rr = 0; rr < 6; ++rr) {
            const float4* row = xp + (pr * 6 + rr) * 6;
            float4 va = row[0], vb = row[1], vc = row[2];
            float4 vd = row[3], ve = row[4], vf = row[5];
            a0 += va.x + va.y + va.z + va.w + vb.x + vb.y;   // cols 0..5
            a1 += vb.z + vb.w + vc.x + vc.y + vc.z + vc.w;   // cols 6..11
            a2 += vd.x + vd.y + vd.z + vd.w + ve.x + ve.y;   // cols 12..17
            a3 += ve.z + ve.w + vf.x + vf.y + vf.z + vf.w;   // cols 18..23
        }
        pooled[pr * 4 + 0] = a0 * (1.f / 36.f);
        pooled[pr * 4 + 1] = a1 * (1.f / 36.f);
        pooled[pr * 4 + 2] = a2 * (1.f / 36.f);
        pooled[pr * 4 + 3] = a3 * (1.f / 36.f);
    }

    // ---- encoding: enc = pooled @ Wenc^T + benc; angles -> cos/sin of half ----
    float ch[4], sh[4];
    #pragma unroll
    for (int j = 0; j < 4; ++j) {
        float e = sW[64 + j];
        #pragma unroll
        for (int k = 0; k < 16; ++k) e = fmaf(pooled[k], sW[j * 16 + k], e);
        const float h = 0.5f * e;
        ch[j] = cosf(h);
        sh[j] = sinf(h);
    }

    // ---- 4-qubit statevector, idx = q0*8 + q1*4 + q2*2 + q3 (wire w -> bit 8>>w)
    float re[16], im[16];
    #pragma unroll
    for (int i = 0; i < 16; ++i) { re[i] = 0.f; im[i] = 0.f; }
    re[0] = 1.f;

    // RY(w): [[c,-s],[s,c]]
    #pragma unroll
    for (int w = 0; w < 4; ++w) {
        const int bit = 8 >> w;
        #pragma unroll
        for (int i = 0; i < 16; ++i) if (!(i & bit)) {
            const int j = i | bit;
            const float r0 = re[i], m0 = im[i], r1 = re[j], m1 = im[j];
            re[i] = ch[w] * r0 - sh[w] * r1;  im[i] = ch[w] * m0 - sh[w] * m1;
            re[j] = sh[w] * r0 + ch[w] * r1;  im[j] = sh[w] * m0 + ch[w] * m1;
        }
    }
    // RZ(w): diag(e^{-ih}, e^{+ih})
    #pragma unroll
    for (int w = 0; w < 4; ++w) {
        const int bit = 8 >> w;
        #pragma unroll
        for (int i = 0; i < 16; ++i) {
            const float sg = (i & bit) ? 1.f : -1.f;
            const float r = re[i], m = im[i];
            re[i] = ch[w] * r - sg * sh[w] * m;
            im[i] = ch[w] * m + sg * sh[w] * r;
        }
    }
    // CNOTs on adjacent wires: pure register swaps
    #define SWAP_AMP(a, b) { float tr = re[a]; re[a] = re[b]; re[b] = tr; \
                             float ti = im[a]; im[a] = im[b]; im[b] = ti; }
    // CNOT(0,1): control bit 8, target bit 4
    SWAP_AMP(8, 12)  SWAP_AMP(9, 13)  SWAP_AMP(10, 14) SWAP_AMP(11, 15)
    // CNOT(1,2): control bit 4, target bit 2
    SWAP_AMP(4, 6)   SWAP_AMP(5, 7)   SWAP_AMP(12, 14) SWAP_AMP(13, 15)
    // CNOT(2,3): control bit 2, target bit 1
    SWAP_AMP(2, 3)   SWAP_AMP(6, 7)   SWAP_AMP(10, 11) SWAP_AMP(14, 15)
    #undef SWAP_AMP

    // RX(w): [[c,-is],[-is,c]]
    #pragma unroll
    for (int w = 0; w < 4; ++w) {
        const int bit = 8 >> w;
        #pragma unroll
        for (int i = 0; i < 16; ++i) if (!(i & bit)) {
            const int j = i | bit;
            const float r0 = re[i], m0 = im[i], r1 = re[j], m1 = im[j];
            re[i] = ch[w] * r0 + sh[w] * m1;  im[i] = ch[w] * m0 - sh[w] * r1;
            re[j] = sh[w] * m0 + ch[w] * r1;  im[j] = ch[w] * m1 - sh[w] * r0;
        }
    }

    // ---- PauliZ expectations ----
    float ez[4];
    #pragma unroll
    for (int w = 0; w < 4; ++w) {
        const int bit = 8 >> w;
        float acc = 0.f;
        #pragma unroll
        for (int i = 0; i < 16; ++i) {
            const float p = re[i] * re[i] + im[i] * im[i];
            acc += (i & bit) ? -p : p;
        }
        ez[w] = acc;
    }

    // ---- MLP: h = relu(ez @ W1^T + b1); out = h @ W2^T + b2 ----
    float o0 = sW[356], o1 = sW[357], o2 = sW[358], o3 = sW[359];
    #pragma unroll
    for (int i = 0; i < 32; ++i) {
        float h = sW[196 + i];
        #pragma unroll
        for (int j = 0; j < 4; ++j) h = fmaf(ez[j], sW[68 + i * 4 + j], h);
        h = fmaxf(h, 0.f);
        o0 = fmaf(h, sW[228 +  0 + i], o0);
        o1 = fmaf(h, sW[228 + 32 + i], o1);
        o2 = fmaf(h, sW[228 + 64 + i], o2);
        o3 = fmaf(h, sW[228 + 96 + i], o3);
    }

    reinterpret_cast<float4*>(out_pre)[s] = make_float4(o0, o1, o2, o3);

    // ---- deterministic block reduction of sum / sumsq per feature ----
    float v[8] = { o0, o1, o2, o3, o0 * o0, o1 * o1, o2 * o2, o3 * o3 };
    #pragma unroll
    for (int off = 32; off; off >>= 1) {
        #pragma unroll
        for (int k = 0; k < 8; ++k) v[k] += __shfl_down(v[k], off);
    }
    __shared__ float red[4][8];
    const int wave = t >> 6, lane = t & 63;
    if (lane == 0) {
        #pragma unroll
        for (int k = 0; k < 8; ++k) red[wave][k] = v[k];
    }
    __syncthreads();
    if (t < 8) {
        partials[blockIdx.x * 8 + t] = red[0][t] + red[1][t] + red[2][t] + red[3][t];
    }
}

// ---------------------------------------------------------------------------
// Kernel 2: reduce 512 block-partials -> scale/shift (8 floats in d_ws).
// ---------------------------------------------------------------------------
__global__ __launch_bounds__(512) void qnat_reduce(
    const float* __restrict__ partials, const float* __restrict__ gamma,
    const float* __restrict__ beta, float* __restrict__ ss)
{
    const int t = threadIdx.x;   // 0..511, one partial row each
    const float4* p4 = reinterpret_cast<const float4*>(partials);
    const float4 a = p4[t * 2], b = p4[t * 2 + 1];
    float v[8] = { a.x, a.y, a.z, a.w, b.x, b.y, b.z, b.w };
    #pragma unroll
    for (int off = 32; off; off >>= 1) {
        #pragma unroll
        for (int k = 0; k < 8; ++k) v[k] += __shfl_down(v[k], off);
    }
    __shared__ float red[8][8];
    const int wave = t >> 6, lane = t & 63;
    if (lane == 0) {
        #pragma unroll
        for (int k = 0; k < 8; ++k) red[wave][k] = v[k];
    }
    __syncthreads();
    if (t < 4) {
        float sum = 0.f, sumsq = 0.f;
        #pragma unroll
        for (int w = 0; w < 8; ++w) { sum += red[w][t]; sumsq += red[w][4 + t]; }
        const float invB  = 1.f / (float)BATCH;
        const float mean  = sum * invB;
        const float var   = sumsq * invB - mean * mean;
        const float scale = gamma[t] / sqrtf(var + 1e-5f);
        ss[t]     = scale;
        ss[4 + t] = beta[t] - mean * scale;
    }
}

// ---------------------------------------------------------------------------
// Kernel 3: apply BN in place on d_out: out = pre * scale[j] + shift[j].
// ---------------------------------------------------------------------------
__global__ __launch_bounds__(256) void qnat_bn(
    float* __restrict__ io, const float* __restrict__ ss)
{
    __shared__ float s8[8];
    if (threadIdx.x < 8) s8[threadIdx.x] = ss[threadIdx.x];
    __syncthreads();
    const int idx = blockIdx.x * 256 + threadIdx.x;   // one sample (float4) each
    float4* p = reinterpret_cast<float4*>(io);
    float4 v = p[idx];
    v.x = fmaf(v.x, s8[0], s8[4]);
    v.y = fmaf(v.y, s8[1], s8[5]);
    v.z = fmaf(v.z, s8[2], s8[6]);
    v.w = fmaf(v.w, s8[3], s8[7]);
    p[idx] = v;
}

extern "C" void kernel_launch(void* const* d_in, const int* in_sizes, int n_in,
                              void* d_out, int out_size, void* d_ws, size_t ws_size,
                              hipStream_t stream)
{
    const float* x     = (const float*)d_in[0];
    const float* Wenc  = (const float*)d_in[1];
    const float* benc  = (const float*)d_in[2];
    const float* W1    = (const float*)d_in[3];
    const float* b1    = (const float*)d_in[4];
    const float* W2    = (const float*)d_in[5];
    const float* b2    = (const float*)d_in[6];
    const float* gamma = (const float*)d_in[7];
    const float* beta  = (const float*)d_in[8];

    float* out      = (float*)d_out;
    float* partials = (float*)d_ws;            // 512 * 8 floats
    float* ss       = partials + NBLK * 8;     // 8 floats (scale[4], shift[4])

    qnat_main<<<NBLK, 256, 0, stream>>>(x, Wenc, benc, W1, b1, W2, b2, out, partials);
    qnat_reduce<<<1, 512, 0, stream>>>(partials, gamma, beta, ss);
    qnat_bn<<<NBLK, 256, 0, stream>>>(out, ss);
}